// Round 5
// baseline (302.813 us; speedup 1.0000x reference)
//
#include <hip/hip_runtime.h>
#include <stdint.h>

#define NN 100000
#define NE 1600000
#define NB 391          // coarse buckets of 256 nodes: bucket = dst >> 8

using u16 = unsigned short;
using u32 = unsigned int;

typedef __attribute__((ext_vector_type(8))) short bf16x8;
typedef __attribute__((ext_vector_type(4))) float f32x4;

__device__ inline u16 f2b(float f){
  u32 u = __float_as_uint(f);
  u32 r = (u + 0x7fffu + ((u >> 16) & 1u)) >> 16;
  return (u16)r;
}

// ---------------- weight prep: fp32 -> bf16, transposed [n][k] ----------------
__global__ void k_prep(const float* __restrict__ Wp1, const float* __restrict__ Ws1,
                       const float* __restrict__ Wn1, const float* __restrict__ Wp2,
                       const float* __restrict__ Ws2, const float* __restrict__ Wn2,
                       u16* __restrict__ wpT1, u16* __restrict__ wc1T,
                       u16* __restrict__ wpT2, u16* __restrict__ wc2T){
  int i = blockIdx.x * 256 + threadIdx.x;
  if (i < 16384){ int n = i >> 7, k = i & 127;
    wpT1[n*128 + k] = f2b(Wp1[k*128 + n]);
    wpT2[n*128 + k] = f2b(Wp2[k*128 + n]);
  }
  if (i < 32768){ int n = i >> 8, k = i & 255;
    float v = (k < 128) ? Ws1[k*128 + n] : Wn1[(k-128)*128 + n];
    wc1T[n*256 + k] = f2b(v);
  }
  if (i < 12288){ int n = i >> 8, k = i & 255;
    float v = 0.f;
    if (n < 40) v = (k < 128) ? Ws2[k*40 + n] : Wn2[(k-128)*40 + n];
    wc2T[n*256 + k] = f2b(v);
  }
}

// ---------------- CSR build: two-pass LDS-binned counting sort ----------------
__global__ __launch_bounds__(256) void k_cb_hist(const int* __restrict__ dst,
                                                 int* __restrict__ cb){
  __shared__ int h[NB];
  for (int i = threadIdx.x; i < NB; i += 256) h[i] = 0;
  __syncthreads();
  int e0 = blockIdx.x * 8192;
  #pragma unroll 4
  for (int j = 0; j < 32; j++){
    int e = e0 + j * 256 + threadIdx.x;
    if (e < NE) atomicAdd(&h[dst[e] >> 8], 1);
  }
  __syncthreads();
  for (int i = threadIdx.x; i < NB; i += 256)
    if (h[i]) atomicAdd(&cb[i], h[i]);
}

__global__ void k_cb_scan(const int* __restrict__ cb, int* __restrict__ cbo,
                          int* __restrict__ curB){
  if (threadIdx.x == 0 && blockIdx.x == 0){
    int a = 0;
    for (int i = 0; i < NB; i++){ cbo[i] = a; curB[i] = a; a += cb[i]; }
    cbo[NB] = a;
  }
}

__global__ __launch_bounds__(256) void k_part(const int* __restrict__ src,
                                              const int* __restrict__ dst,
                                              int* __restrict__ curB,
                                              int2* __restrict__ part){
  __shared__ int hist[NB], scn[NB], cur[NB], base[NB];
  __shared__ int2 stage[4096];
  const int tid = threadIdx.x;
  const int e0 = blockIdx.x * 4096;
  const int cnt = min(4096, NE - e0);
  for (int i = tid; i < NB; i += 256) hist[i] = 0;
  __syncthreads();
  int2 ed[16];
  #pragma unroll
  for (int j = 0; j < 16; j++){
    int e = e0 + j * 256 + tid;
    if (e < NE){
      ed[j].x = src[e]; ed[j].y = dst[e];
      atomicAdd(&hist[ed[j].y >> 8], 1);
    }
  }
  __syncthreads();
  for (int i = tid; i < NB; i += 256)
    base[i] = hist[i] ? atomicAdd(&curB[i], hist[i]) : 0;
  if (tid == 0){
    int a = 0;
    for (int i = 0; i < NB; i++){ scn[i] = a; cur[i] = a; a += hist[i]; }
  }
  __syncthreads();
  #pragma unroll
  for (int j = 0; j < 16; j++){
    int e = e0 + j * 256 + tid;
    if (e < NE){
      int slot = atomicAdd(&cur[ed[j].y >> 8], 1);
      stage[slot] = ed[j];
    }
  }
  __syncthreads();
  for (int i = tid; i < cnt; i += 256){
    int2 p = stage[i];
    int b = p.y >> 8;
    part[base[b] + (i - scn[b])] = p;
  }
}

__global__ __launch_bounds__(256) void k_bsort(const int2* __restrict__ part,
                                               const int* __restrict__ cbo,
                                               int* __restrict__ rp,
                                               int* __restrict__ esrc){
  __shared__ int cnt[256], sc[256], cur[256];
  const int tid = threadIdx.x;
  const int b = blockIdx.x;
  const int lo = cbo[b], hi = cbo[b + 1];
  cnt[tid] = 0;
  __syncthreads();
  for (int i = lo + tid; i < hi; i += 256)
    atomicAdd(&cnt[part[i].y & 255], 1);
  __syncthreads();
  sc[tid] = cnt[tid];
  __syncthreads();
  #pragma unroll
  for (int off = 1; off < 256; off <<= 1){
    int t = (tid >= off) ? sc[tid - off] : 0;
    __syncthreads();
    sc[tid] += t;
    __syncthreads();
  }
  int ex = sc[tid] - cnt[tid];
  int n = (b << 8) + tid;
  if (n < NN) rp[n] = lo + ex;
  if (b == NB - 1 && tid == 0) rp[NN] = hi;
  cur[tid] = lo + ex;
  __syncthreads();
  for (int i = lo + tid; i < hi; i += 256){
    int2 p = part[i];
    int pos = atomicAdd(&cur[p.y & 255], 1);
    esrc[pos] = p.x;
  }
}

// ---------------- plain bf16 MFMA GEMM (used for hp = relu(x@Wp+bp)) ---------
// Wt pre-transposed bf16 [NOUT][K]. 16x16x32 MFMA; frag layouts m89-verified.
template<int K, int NOUT, int NOUTR, int BM, int NT,
         bool A1F32, bool RELU, bool OUTF32>
__global__ __launch_bounds__(NT)
void k_gemm(const void* __restrict__ A1p, const u16* __restrict__ Wt,
            const float* __restrict__ bias, void* __restrict__ outp)
{
  constexpr int KSTEP = 64;
  constexpr int KP = KSTEP + 8;     // 144 B rows: 16B-aligned, 2-way banks (free)
  constexpr int NTI = NOUT / 16;
  __shared__ u16 A_lds[BM * KP];
  __shared__ u16 W_lds[NOUT * KP];
  const int tid  = threadIdx.x;
  const int row0 = blockIdx.x * BM;
  const int wave = tid >> 6, lane = tid & 63;
  const int koff = (lane >> 4) * 8;
  const u16* Ar = &A_lds[(wave * 16 + (lane & 15)) * KP];

  f32x4 acc[NTI] = {};

  #pragma unroll
  for (int k0 = 0; k0 < K; k0 += KSTEP){
    if (k0) __syncthreads();
    for (int c = tid; c < NOUT * 8; c += NT){
      int n = c >> 3, kc = c & 7;
      *(uint4*)&W_lds[n * KP + kc * 8] = *(const uint4*)&Wt[n * K + k0 + kc * 8];
    }
    if (A1F32){
      const float* A = (const float*)A1p;
      for (int c = tid; c < BM * 16; c += NT){
        int rl = c >> 4, kc = c & 15;
        int gr = row0 + rl;
        float4 v = make_float4(0.f, 0.f, 0.f, 0.f);
        if (gr < NN) v = *(const float4*)&A[(size_t)gr * 128 + k0 + kc * 4];
        ushort4 o; o.x = f2b(v.x); o.y = f2b(v.y); o.z = f2b(v.z); o.w = f2b(v.w);
        *(ushort4*)&A_lds[rl * KP + kc * 4] = o;
      }
    } else {
      const u16* A = (const u16*)A1p;
      for (int c = tid; c < BM * 8; c += NT){
        int rl = c >> 3, kc = c & 7;
        int gr = row0 + rl;
        uint4 v = make_uint4(0, 0, 0, 0);
        if (gr < NN) v = *(const uint4*)&A[(size_t)gr * 128 + k0 + kc * 8];
        *(uint4*)&A_lds[rl * KP + kc * 8] = v;
      }
    }
    __syncthreads();

    bf16x8 af0 = *(const bf16x8*)&Ar[koff];
    bf16x8 af1 = *(const bf16x8*)&Ar[32 + koff];
    #pragma unroll
    for (int nt = 0; nt < NTI; nt++){
      const u16* Wr = &W_lds[(nt * 16 + (lane & 15)) * KP];
      bf16x8 b0 = *(const bf16x8*)&Wr[koff];
      bf16x8 b1 = *(const bf16x8*)&Wr[32 + koff];
      acc[nt] = __builtin_amdgcn_mfma_f32_16x16x32_bf16(af0, b0, acc[nt], 0, 0, 0);
      acc[nt] = __builtin_amdgcn_mfma_f32_16x16x32_bf16(af1, b1, acc[nt], 0, 0, 0);
    }
  }

  const int colb = lane & 15;
  const int rowl = wave * 16 + ((lane >> 4) << 2);
  #pragma unroll
  for (int nt = 0; nt < NTI; nt++){
    int col = nt * 16 + colb;
    if (col >= NOUTR) continue;
    float bv = bias[col];
    #pragma unroll
    for (int r = 0; r < 4; r++){
      int gr = row0 + rowl + r;
      if (gr >= NN) continue;
      float v = acc[nt][r] + bv;
      if (RELU) v = fmaxf(v, 0.f);
      if (OUTF32) ((float*)outp)[(size_t)gr * NOUTR + col] = v;
      else        ((u16*)outp)[(size_t)gr * NOUTR + col] = f2b(v);
    }
  }
}

// -------- fused segment-max + concat GEMM: out = [A1 | segmax(hp)] @ Wt^T + b
// K fixed at 256 (128 from A1, 128 from the gathered aggregation).
// Each of 8 waves owns 16 output rows == the 16 nodes it aggregates, so the
// aggregation result lives in a wave-private LDS band (G_lds) with NO cross-
// wave sync. K-steps 0,1 stage A1; K-steps 2,3 read G_lds directly.
// Messages are post-ReLU (>=0): packed-bf16 max == v_pk_max_u16, init 0;
// zero-in-degree nodes -> 0 (matches where(isfinite(max),max,0)).
template<int NOUT, int NOUTR, bool A1F32, bool RELU, bool OUTF32>
__global__ __launch_bounds__(512)
void k_fgemm(const void* __restrict__ A1p, const u16* __restrict__ hp,
             const int* __restrict__ rp, const int* __restrict__ esrc,
             const u16* __restrict__ Wt, const float* __restrict__ bias,
             void* __restrict__ outp)
{
  constexpr int BM = 128, NT = 512, KSTEP = 64;
  constexpr int KP  = KSTEP + 8;    // x-staging pitch (144 B rows)
  constexpr int KP2 = 136;          // agg band pitch (272 B rows, 16B-aligned)
  constexpr int NTI = NOUT / 16;
  __shared__ u16 A_lds[BM * KP];
  __shared__ u16 W_lds[NOUT * KP];
  __shared__ u16 G_lds[BM * KP2];
  const int tid  = threadIdx.x;
  const int row0 = blockIdx.x * BM;
  const int wave = tid >> 6, lane = tid & 63;
  const int half = lane >> 5, l32 = lane & 31;
  const int koff = (lane >> 4) * 8;

  // ---- aggregation phase: wave w gathers nodes row0+w*16 .. +15 ----
  for (int j = 0; j < 16; j++){
    int node = row0 + wave * 16 + j;
    u32 m0 = 0, m1 = 0;
    if (node < NN){
      int lo = rp[node], hi = rp[node + 1];
      for (int i = lo; i < hi; i += 16){
        int s[8];
        #pragma unroll
        for (int t = 0; t < 8; t++){
          int ii = i + 2 * t + half; if (ii >= hi) ii = hi - 1;
          s[t] = esrc[ii];
        }
        uint2 v[8];
        #pragma unroll
        for (int t = 0; t < 8; t++)
          v[t] = *(const uint2*)&hp[(size_t)s[t] * 128 + l32 * 4];
        #pragma unroll
        for (int t = 0; t < 8; t++){
          asm("v_pk_max_u16 %0, %0, %1" : "+v"(m0) : "v"(v[t].x));
          asm("v_pk_max_u16 %0, %0, %1" : "+v"(m1) : "v"(v[t].y));
        }
      }
    }
    u32 t0 = (u32)__shfl_xor((int)m0, 32);
    u32 t1 = (u32)__shfl_xor((int)m1, 32);
    asm("v_pk_max_u16 %0, %0, %1" : "+v"(m0) : "v"(t0));
    asm("v_pk_max_u16 %0, %0, %1" : "+v"(m1) : "v"(t1));
    if (half == 0)
      *(uint2*)&G_lds[(wave * 16 + j) * KP2 + l32 * 4] = make_uint2(m0, m1);
  }
  // no __syncthreads needed for G_lds: each wave reads only its own band

  const u16* Ar = &A_lds[(wave * 16 + (lane & 15)) * KP];
  const u16* Gr = &G_lds[(wave * 16 + (lane & 15)) * KP2];

  f32x4 acc[NTI] = {};

  #pragma unroll
  for (int k0 = 0; k0 < 256; k0 += KSTEP){
    if (k0) __syncthreads();
    // stage W chunk [NOUT][64]
    for (int c = tid; c < NOUT * 8; c += NT){
      int n = c >> 3, kc = c & 7;
      *(uint4*)&W_lds[n * KP + kc * 8] = *(const uint4*)&Wt[n * 256 + k0 + kc * 8];
    }
    // stage A1 chunk for k0<128 (x half); k0>=128 reads G_lds directly
    if (k0 < 128){
      if (A1F32){
        const float* A = (const float*)A1p;
        for (int c = tid; c < BM * 16; c += NT){
          int rl = c >> 4, kc = c & 15;
          int gr = row0 + rl;
          float4 v = make_float4(0.f, 0.f, 0.f, 0.f);
          if (gr < NN) v = *(const float4*)&A[(size_t)gr * 128 + k0 + kc * 4];
          ushort4 o; o.x = f2b(v.x); o.y = f2b(v.y); o.z = f2b(v.z); o.w = f2b(v.w);
          *(ushort4*)&A_lds[rl * KP + kc * 4] = o;
        }
      } else {
        const u16* A = (const u16*)A1p;
        for (int c = tid; c < BM * 8; c += NT){
          int rl = c >> 3, kc = c & 7;
          int gr = row0 + rl;
          uint4 v = make_uint4(0, 0, 0, 0);
          if (gr < NN) v = *(const uint4*)&A[(size_t)gr * 128 + k0 + kc * 8];
          *(uint4*)&A_lds[rl * KP + kc * 8] = v;
        }
      }
    }
    __syncthreads();

    bf16x8 af0, af1;
    if (k0 < 128){
      af0 = *(const bf16x8*)&Ar[koff];
      af1 = *(const bf16x8*)&Ar[32 + koff];
    } else {
      af0 = *(const bf16x8*)&Gr[(k0 - 128) + koff];
      af1 = *(const bf16x8*)&Gr[(k0 - 128) + 32 + koff];
    }
    #pragma unroll
    for (int nt = 0; nt < NTI; nt++){
      const u16* Wr = &W_lds[(nt * 16 + (lane & 15)) * KP];
      bf16x8 b0 = *(const bf16x8*)&Wr[koff];
      bf16x8 b1 = *(const bf16x8*)&Wr[32 + koff];
      acc[nt] = __builtin_amdgcn_mfma_f32_16x16x32_bf16(af0, b0, acc[nt], 0, 0, 0);
      acc[nt] = __builtin_amdgcn_mfma_f32_16x16x32_bf16(af1, b1, acc[nt], 0, 0, 0);
    }
  }

  const int colb = lane & 15;
  const int rowl = wave * 16 + ((lane >> 4) << 2);
  #pragma unroll
  for (int nt = 0; nt < NTI; nt++){
    int col = nt * 16 + colb;
    if (col >= NOUTR) continue;
    float bv = bias[col];
    #pragma unroll
    for (int r = 0; r < 4; r++){
      int gr = row0 + rowl + r;
      if (gr >= NN) continue;
      float v = acc[nt][r] + bv;
      if (RELU) v = fmaxf(v, 0.f);
      if (OUTF32) ((float*)outp)[(size_t)gr * NOUTR + col] = v;
      else        ((u16*)outp)[(size_t)gr * NOUTR + col] = f2b(v);
    }
  }
}

// ---------------- host launch ----------------
extern "C" void kernel_launch(void* const* d_in, const int* in_sizes, int n_in,
                              void* d_out, int out_size, void* d_ws, size_t ws_size,
                              hipStream_t stream){
  const float* x   = (const float*)d_in[0];
  const int*   src = (const int*)d_in[1];
  const int*   dst = (const int*)d_in[2];
  const float* Wp1 = (const float*)d_in[3];
  const float* bp1 = (const float*)d_in[4];
  const float* Ws1 = (const float*)d_in[5];
  const float* Wn1 = (const float*)d_in[6];
  const float* b1  = (const float*)d_in[7];
  const float* Wp2 = (const float*)d_in[8];
  const float* bp2 = (const float*)d_in[9];
  const float* Ws2 = (const float*)d_in[10];
  const float* Wn2 = (const float*)d_in[11];
  const float* b2  = (const float*)d_in[12];

  char* ws = (char*)d_ws;
  u16* wpT1 = (u16*)(ws + 0);            // 128x128 bf16
  u16* wc1T = (u16*)(ws + 32768);        // 128x256 bf16
  u16* wpT2 = (u16*)(ws + 98304);        // 128x128 bf16
  u16* wc2T = (u16*)(ws + 131072);       // 48x256 bf16 (cols 40..47 zero)
  int* cb   = (int*)(ws + 155648);       // NB bucket counts
  int* cbo  = (int*)(ws + 157696);       // NB+1 bucket offsets
  int* curB = (int*)(ws + 159744);       // NB reservation cursors
  int* rp   = (int*)(ws + 161792);       // N+1 row pointers
  int2* part= (int2*)(ws + 561920);      // E pairs, bucket-grouped (12.8 MB)
  u16* h    = (u16*)(ws + 561920);       // N x 128 bf16 (aliases part; part dead first)
  int* esrc = (int*)(ws + 26161920);     // E src ids sorted by dst (6.4 MB)
  u16* hp   = (u16*)(ws + 32561920);     // N x 128 bf16

  hipMemsetAsync(cb, 0, NB * sizeof(int), stream);
  k_prep<<<128, 256, 0, stream>>>(Wp1, Ws1, Wn1, Wp2, Ws2, Wn2, wpT1, wc1T, wpT2, wc2T);
  k_cb_hist<<<(NE + 8191) / 8192, 256, 0, stream>>>(dst, cb);
  k_cb_scan<<<1, 64, 0, stream>>>(cb, cbo, curB);
  k_part<<<(NE + 4095) / 4096, 256, 0, stream>>>(src, dst, curB, part);
  k_bsort<<<NB, 256, 0, stream>>>(part, cbo, rp, esrc);

  // layer 1: hp = relu(x@Wp1+bp1); h = relu(x@Ws1 + segmax(hp)@Wn1 + b1)
  k_gemm<128,128,128, 64,256, true ,true ,false>
      <<<(NN + 63) / 64, 256, 0, stream>>>(x, wpT1, bp1, hp);
  k_fgemm<128,128, true ,true ,false>
      <<<(NN + 127) / 128, 512, 0, stream>>>(x, hp, rp, esrc, wc1T, b1, h);
  // layer 2: hp = relu(h@Wp2+bp2); out = h@Ws2 + segmax(hp)@Wn2 + b2
  k_gemm<128,128,128, 64,256, false,true ,false>
      <<<(NN + 63) / 64, 256, 0, stream>>>(h, wpT2, bp2, hp);
  k_fgemm< 48, 40, false,false,true >
      <<<(NN + 127) / 128, 512, 0, stream>>>(h, hp, rp, esrc, wc2T, b2, d_out);
}

// Round 6
// 268.561 us; speedup vs baseline: 1.1275x; 1.1275x over previous
//
#include <hip/hip_runtime.h>
#include <stdint.h>

#define NN 100000
#define NE 1600000
#define NB 196          // coarse buckets of 512 nodes: bucket = dst >> 9

using u16 = unsigned short;
using u32 = unsigned int;

typedef __attribute__((ext_vector_type(8))) short bf16x8;
typedef __attribute__((ext_vector_type(4))) float f32x4;

__device__ inline u16 f2b(float f){
  u32 u = __float_as_uint(f);
  u32 r = (u + 0x7fffu + ((u >> 16) & 1u)) >> 16;
  return (u16)r;
}

// ------- weight prep: fp32 -> bf16, transposed [n][k]; also clears cb -------
__global__ void k_prep(const float* __restrict__ Wp1, const float* __restrict__ Ws1,
                       const float* __restrict__ Wn1, const float* __restrict__ Wp2,
                       const float* __restrict__ Ws2, const float* __restrict__ Wn2,
                       u16* __restrict__ wpT1, u16* __restrict__ wc1T,
                       u16* __restrict__ wpT2, u16* __restrict__ wc2T,
                       int* __restrict__ cb){
  int i = blockIdx.x * 256 + threadIdx.x;
  if (i < NB) cb[i] = 0;
  if (i < 16384){ int n = i >> 7, k = i & 127;
    wpT1[n*128 + k] = f2b(Wp1[k*128 + n]);
    wpT2[n*128 + k] = f2b(Wp2[k*128 + n]);
  }
  if (i < 32768){ int n = i >> 8, k = i & 255;
    float v = (k < 128) ? Ws1[k*128 + n] : Wn1[(k-128)*128 + n];
    wc1T[n*256 + k] = f2b(v);
  }
  if (i < 12288){ int n = i >> 8, k = i & 255;
    float v = 0.f;
    if (n < 40) v = (k < 128) ? Ws2[k*40 + n] : Wn2[(k-128)*40 + n];
    wc2T[n*256 + k] = f2b(v);
  }
}

// ---------------- CSR build: two-pass LDS-binned counting sort ----------------
__global__ __launch_bounds__(256) void k_cb_hist(const int* __restrict__ dst,
                                                 int* __restrict__ cb){
  __shared__ int h[NB];
  for (int i = threadIdx.x; i < NB; i += 256) h[i] = 0;
  __syncthreads();
  int e0 = blockIdx.x * 8192;
  #pragma unroll 4
  for (int j = 0; j < 32; j++){
    int e = e0 + j * 256 + threadIdx.x;
    if (e < NE) atomicAdd(&h[dst[e] >> 9], 1);
  }
  __syncthreads();
  for (int i = threadIdx.x; i < NB; i += 256)
    if (h[i]) atomicAdd(&cb[i], h[i]);
}

// parallel exclusive scan of NB (<=256) bucket counts
__global__ __launch_bounds__(256) void k_cb_scan(const int* __restrict__ cb,
                                                 int* __restrict__ cbo,
                                                 int* __restrict__ curB){
  __shared__ int s[256];
  int tid = threadIdx.x;
  int v = (tid < NB) ? cb[tid] : 0;
  s[tid] = v;
  __syncthreads();
  #pragma unroll
  for (int off = 1; off < 256; off <<= 1){
    int t = (tid >= off) ? s[tid - off] : 0;
    __syncthreads();
    s[tid] += t;
    __syncthreads();
  }
  int ex = s[tid] - v;
  if (tid < NB){ cbo[tid] = ex; curB[tid] = ex; }
  if (tid == 255) cbo[NB] = s[255];
}

__global__ __launch_bounds__(256) void k_part(const int* __restrict__ src,
                                              const int* __restrict__ dst,
                                              int* __restrict__ curB,
                                              int2* __restrict__ part){
  __shared__ int hist[256], scn[256], cur[256], base[256];
  __shared__ int2 stage[4096];
  const int tid = threadIdx.x;
  const int e0 = blockIdx.x * 4096;
  const int cnt = min(4096, NE - e0);
  hist[tid] = 0;
  __syncthreads();
  int2 ed[16];
  #pragma unroll
  for (int j = 0; j < 16; j++){
    int e = e0 + j * 256 + tid;
    if (e < NE){
      ed[j].x = src[e]; ed[j].y = dst[e];
      atomicAdd(&hist[ed[j].y >> 9], 1);
    }
  }
  __syncthreads();
  int hv = hist[tid];
  base[tid] = (tid < NB && hv) ? atomicAdd(&curB[tid], hv) : 0;
  // parallel exclusive scan of hist
  scn[tid] = hv;
  __syncthreads();
  #pragma unroll
  for (int off = 1; off < 256; off <<= 1){
    int t = (tid >= off) ? scn[tid - off] : 0;
    __syncthreads();
    scn[tid] += t;
    __syncthreads();
  }
  int ex = scn[tid] - hv;
  scn[tid] = ex;
  cur[tid] = ex;
  __syncthreads();
  #pragma unroll
  for (int j = 0; j < 16; j++){
    int e = e0 + j * 256 + tid;
    if (e < NE){
      int slot = atomicAdd(&cur[ed[j].y >> 9], 1);
      stage[slot] = ed[j];
    }
  }
  __syncthreads();
  for (int i = tid; i < cnt; i += 256){
    int2 p = stage[i];
    int b = p.y >> 9;
    part[base[b] + (i - scn[b])] = p;
  }
}

__global__ __launch_bounds__(512) void k_bsort(const int2* __restrict__ part,
                                               const int* __restrict__ cbo,
                                               int* __restrict__ rp,
                                               int* __restrict__ esrc){
  __shared__ int cnt[512], sc[512], cur[512];
  const int tid = threadIdx.x;
  const int b = blockIdx.x;
  const int lo = cbo[b], hi = cbo[b + 1];
  cnt[tid] = 0;
  __syncthreads();
  for (int i = lo + tid; i < hi; i += 512)
    atomicAdd(&cnt[part[i].y & 511], 1);
  __syncthreads();
  sc[tid] = cnt[tid];
  __syncthreads();
  #pragma unroll
  for (int off = 1; off < 512; off <<= 1){
    int t = (tid >= off) ? sc[tid - off] : 0;
    __syncthreads();
    sc[tid] += t;
    __syncthreads();
  }
  int ex = sc[tid] - cnt[tid];
  int n = (b << 9) + tid;
  if (n < NN) rp[n] = lo + ex;
  if (b == NB - 1 && tid == 0) rp[NN] = hi;
  cur[tid] = lo + ex;
  __syncthreads();
  for (int i = lo + tid; i < hi; i += 512){
    int2 p = part[i];
    int pos = atomicAdd(&cur[p.y & 511], 1);
    esrc[pos] = p.x;
  }
}

// ---------------- segment-max aggregation (one wave per node) ----------------
// post-ReLU messages (>=0): packed-bf16 max == v_pk_max_u16, init 0 handles
// zero-in-degree. Half-wave per row (32x8B), 16 edges in flight per wave.
__global__ void k_agg(const u16* __restrict__ hp, const int* __restrict__ rp,
                      const int* __restrict__ esrc, u16* __restrict__ agg){
  int node = blockIdx.x * 4 + (threadIdx.x >> 6);
  if (node >= NN) return;
  const int lane = threadIdx.x & 63;
  const int half = lane >> 5;
  const int l32  = lane & 31;
  const int lo = rp[node], hi = rp[node + 1];
  u32 m0 = 0, m1 = 0;
  for (int i = lo; i < hi; i += 16){
    int s[8];
    #pragma unroll
    for (int j = 0; j < 8; j++){
      int ii = i + 2 * j + half; if (ii >= hi) ii = hi - 1;
      s[j] = esrc[ii];
    }
    uint2 v[8];
    #pragma unroll
    for (int j = 0; j < 8; j++)
      v[j] = *(const uint2*)&hp[(size_t)s[j] * 128 + l32 * 4];
    #pragma unroll
    for (int j = 0; j < 8; j++){
      asm("v_pk_max_u16 %0, %0, %1" : "+v"(m0) : "v"(v[j].x));
      asm("v_pk_max_u16 %0, %0, %1" : "+v"(m1) : "v"(v[j].y));
    }
  }
  u32 t0 = (u32)__shfl_xor((int)m0, 32);
  u32 t1 = (u32)__shfl_xor((int)m1, 32);
  asm("v_pk_max_u16 %0, %0, %1" : "+v"(m0) : "v"(t0));
  asm("v_pk_max_u16 %0, %0, %1" : "+v"(m1) : "v"(t1));
  if (half == 0)
    *(uint2*)&agg[(size_t)node * 128 + l32 * 4] = make_uint2(m0, m1);
}

// ---------------- bf16 MFMA GEMM: out = [A1|A2] @ Wt^T + bias (opt relu) -----
// Wt pre-transposed bf16 [NOUT][K]. 16x16x32 MFMA; frag layouts m89-verified.
template<int K, int NOUT, int NOUTR, int BM, int NT,
         bool A1F32, bool HASA2, bool RELU, bool OUTF32>
__global__ __launch_bounds__(NT)
void k_gemm(const void* __restrict__ A1p, const u16* __restrict__ A2,
            const u16* __restrict__ Wt, const float* __restrict__ bias,
            void* __restrict__ outp)
{
  constexpr int KSTEP = 64;
  constexpr int KP = KSTEP + 8;     // 144 B rows: 16B-aligned, conflict-free frag reads
  constexpr int NTI = NOUT / 16;
  __shared__ u16 A_lds[BM * KP];
  __shared__ u16 W_lds[NOUT * KP];
  const int tid  = threadIdx.x;
  const int row0 = blockIdx.x * BM;
  const int wave = tid >> 6, lane = tid & 63;
  const int koff = (lane >> 4) * 8;
  const u16* Ar = &A_lds[(wave * 16 + (lane & 15)) * KP];

  f32x4 acc[NTI] = {};

  #pragma unroll
  for (int k0 = 0; k0 < K; k0 += KSTEP){
    if (k0) __syncthreads();
    for (int c = tid; c < NOUT * 8; c += NT){
      int n = c >> 3, kc = c & 7;
      *(uint4*)&W_lds[n * KP + kc * 8] = *(const uint4*)&Wt[n * K + k0 + kc * 8];
    }
    if (A1F32 && k0 < 128){
      const float* A = (const float*)A1p;
      for (int c = tid; c < BM * 16; c += NT){
        int rl = c >> 4, kc = c & 15;
        int gr = row0 + rl;
        float4 v = make_float4(0.f, 0.f, 0.f, 0.f);
        if (gr < NN) v = *(const float4*)&A[(size_t)gr * 128 + k0 + kc * 4];
        ushort4 o; o.x = f2b(v.x); o.y = f2b(v.y); o.z = f2b(v.z); o.w = f2b(v.w);
        *(ushort4*)&A_lds[rl * KP + kc * 4] = o;
      }
    } else {
      const u16* A = (HASA2 && k0 >= 128) ? A2 : (const u16*)A1p;
      int cb2 = (HASA2 && k0 >= 128) ? (k0 - 128) : k0;
      for (int c = tid; c < BM * 8; c += NT){
        int rl = c >> 3, kc = c & 7;
        int gr = row0 + rl;
        uint4 v = make_uint4(0, 0, 0, 0);
        if (gr < NN) v = *(const uint4*)&A[(size_t)gr * 128 + cb2 + kc * 8];
        *(uint4*)&A_lds[rl * KP + kc * 8] = v;
      }
    }
    __syncthreads();

    bf16x8 af0 = *(const bf16x8*)&Ar[koff];
    bf16x8 af1 = *(const bf16x8*)&Ar[32 + koff];
    #pragma unroll
    for (int nt = 0; nt < NTI; nt++){
      const u16* Wr = &W_lds[(nt * 16 + (lane & 15)) * KP];
      bf16x8 b0 = *(const bf16x8*)&Wr[koff];
      bf16x8 b1 = *(const bf16x8*)&Wr[32 + koff];
      acc[nt] = __builtin_amdgcn_mfma_f32_16x16x32_bf16(af0, b0, acc[nt], 0, 0, 0);
      acc[nt] = __builtin_amdgcn_mfma_f32_16x16x32_bf16(af1, b1, acc[nt], 0, 0, 0);
    }
  }

  const int colb = lane & 15;
  const int rowl = wave * 16 + ((lane >> 4) << 2);
  #pragma unroll
  for (int nt = 0; nt < NTI; nt++){
    int col = nt * 16 + colb;
    if (col >= NOUTR) continue;
    float bv = bias[col];
    #pragma unroll
    for (int r = 0; r < 4; r++){
      int gr = row0 + rowl + r;
      if (gr >= NN) continue;
      float v = acc[nt][r] + bv;
      if (RELU) v = fmaxf(v, 0.f);
      if (OUTF32) ((float*)outp)[(size_t)gr * NOUTR + col] = v;
      else        ((u16*)outp)[(size_t)gr * NOUTR + col] = f2b(v);
    }
  }
}

// ------ concat GEMM layer1 + fused pool2:
//   h  = relu([x | agg] @ Wc1^T + b1)          (main loop, as k_gemm)
//   hp = relu(h @ Wp2^T + bp2)                 (per-wave tail; h rows live in acc)
// Tail: one barrier, then each wave writes its 16 h-rows to a wave-private LDS
// band (pitch 136) + global h, then MFMAs against wpT2 read from L2 (32KB hot).
__global__ __launch_bounds__(512)
void k_cgemm(const float* __restrict__ x, const u16* __restrict__ agg,
             const u16* __restrict__ Wc, const float* __restrict__ b1,
             const u16* __restrict__ wp2T, const float* __restrict__ bp2,
             u16* __restrict__ h, u16* __restrict__ hp)
{
  constexpr int BM = 128, NT = 512, KSTEP = 64, KP = 72, KPB = 136;
  __shared__ u16 S[128 * KP * 2];          // main: [0,9216)=A, [9216,18432)=W ; tail: 128x136 band
  u16* A_lds = S;
  u16* W_lds = S + 128 * KP;
  const int tid  = threadIdx.x;
  const int row0 = blockIdx.x * BM;
  const int wave = tid >> 6, lane = tid & 63;
  const int koff = (lane >> 4) * 8;
  const u16* Ar = &A_lds[(wave * 16 + (lane & 15)) * KP];

  f32x4 acc[8] = {};

  #pragma unroll
  for (int k0 = 0; k0 < 256; k0 += KSTEP){
    if (k0) __syncthreads();
    for (int c = tid; c < 128 * 8; c += NT){
      int n = c >> 3, kc = c & 7;
      *(uint4*)&W_lds[n * KP + kc * 8] = *(const uint4*)&Wc[n * 256 + k0 + kc * 8];
    }
    if (k0 < 128){
      for (int c = tid; c < BM * 16; c += NT){
        int rl = c >> 4, kc = c & 15;
        int gr = row0 + rl;
        float4 v = make_float4(0.f, 0.f, 0.f, 0.f);
        if (gr < NN) v = *(const float4*)&x[(size_t)gr * 128 + k0 + kc * 4];
        ushort4 o; o.x = f2b(v.x); o.y = f2b(v.y); o.z = f2b(v.z); o.w = f2b(v.w);
        *(ushort4*)&A_lds[rl * KP + kc * 4] = o;
      }
    } else {
      for (int c = tid; c < BM * 8; c += NT){
        int rl = c >> 3, kc = c & 7;
        int gr = row0 + rl;
        uint4 v = make_uint4(0, 0, 0, 0);
        if (gr < NN) v = *(const uint4*)&agg[(size_t)gr * 128 + (k0 - 128) + kc * 8];
        *(uint4*)&A_lds[rl * KP + kc * 8] = v;
      }
    }
    __syncthreads();

    bf16x8 af0 = *(const bf16x8*)&Ar[koff];
    bf16x8 af1 = *(const bf16x8*)&Ar[32 + koff];
    #pragma unroll
    for (int nt = 0; nt < 8; nt++){
      const u16* Wr = &W_lds[(nt * 16 + (lane & 15)) * KP];
      bf16x8 b0 = *(const bf16x8*)&Wr[koff];
      bf16x8 b1 = *(const bf16x8*)&Wr[32 + koff];
      acc[nt] = __builtin_amdgcn_mfma_f32_16x16x32_bf16(af0, b0, acc[nt], 0, 0, 0);
      acc[nt] = __builtin_amdgcn_mfma_f32_16x16x32_bf16(af1, b1, acc[nt], 0, 0, 0);
    }
  }

  __syncthreads();   // everyone done reading A_lds/W_lds; S becomes the h band

  const int colb = lane & 15;
  const int q4   = (lane >> 4) << 2;
  const int rowl = wave * 16 + q4;
  // write h: global bf16 + wave-private band rows [wave*16 .. +15], pitch 136
  #pragma unroll
  for (int nt = 0; nt < 8; nt++){
    int col = nt * 16 + colb;
    float bv = b1[col];
    #pragma unroll
    for (int r = 0; r < 4; r++){
      float v = fmaxf(acc[nt][r] + bv, 0.f);
      u16 hb = f2b(v);
      S[(rowl + r) * KPB + col] = hb;
      int gr = row0 + rowl + r;
      if (gr < NN) h[(size_t)gr * 128 + col] = hb;
    }
  }
  // no barrier: each wave reads only its own band rows (compiler orders LDS w->r)
  const int bandrow = (wave * 16 + (lane & 15)) * KPB;
  bf16x8 af[4];
  #pragma unroll
  for (int kf = 0; kf < 4; kf++)
    af[kf] = *(const bf16x8*)&S[bandrow + kf * 32 + koff];

  f32x4 acc2[8] = {};
  #pragma unroll
  for (int nt = 0; nt < 8; nt++){
    #pragma unroll
    for (int kf = 0; kf < 4; kf++){
      bf16x8 bf = *(const bf16x8*)&wp2T[(nt * 16 + colb) * 128 + kf * 32 + koff];
      acc2[nt] = __builtin_amdgcn_mfma_f32_16x16x32_bf16(af[kf], bf, acc2[nt], 0, 0, 0);
    }
  }
  #pragma unroll
  for (int nt = 0; nt < 8; nt++){
    int col = nt * 16 + colb;
    float bv = bp2[col];
    #pragma unroll
    for (int r = 0; r < 4; r++){
      int gr = row0 + rowl + r;
      if (gr < NN)
        hp[(size_t)gr * 128 + col] = f2b(fmaxf(acc2[nt][r] + bv, 0.f));
    }
  }
}

// ---------------- host launch ----------------
extern "C" void kernel_launch(void* const* d_in, const int* in_sizes, int n_in,
                              void* d_out, int out_size, void* d_ws, size_t ws_size,
                              hipStream_t stream){
  const float* x   = (const float*)d_in[0];
  const int*   src = (const int*)d_in[1];
  const int*   dst = (const int*)d_in[2];
  const float* Wp1 = (const float*)d_in[3];
  const float* bp1 = (const float*)d_in[4];
  const float* Ws1 = (const float*)d_in[5];
  const float* Wn1 = (const float*)d_in[6];
  const float* b1  = (const float*)d_in[7];
  const float* Wp2 = (const float*)d_in[8];
  const float* bp2 = (const float*)d_in[9];
  const float* Ws2 = (const float*)d_in[10];
  const float* Wn2 = (const float*)d_in[11];
  const float* b2  = (const float*)d_in[12];

  char* ws = (char*)d_ws;
  u16* wpT1 = (u16*)(ws + 0);            // 128x128 bf16
  u16* wc1T = (u16*)(ws + 32768);        // 128x256 bf16
  u16* wpT2 = (u16*)(ws + 98304);        // 128x128 bf16
  u16* wc2T = (u16*)(ws + 131072);       // 48x256 bf16 (cols 40..47 zero)
  int* cb   = (int*)(ws + 155648);       // NB bucket counts
  int* cbo  = (int*)(ws + 157696);       // NB+1 bucket offsets
  int* curB = (int*)(ws + 159744);       // NB reservation cursors
  int* rp   = (int*)(ws + 161792);       // N+1 row pointers
  int2* part= (int2*)(ws + 561920);      // E pairs, bucket-grouped (12.8 MB)
  u16* h    = (u16*)(ws + 561920);       // N x 128 bf16 (aliases part; part dead first)
  int* esrc = (int*)(ws + 26161920);     // E src ids sorted by dst (6.4 MB)
  u16* hp   = (u16*)(ws + 32561920);     // N x 128 bf16
  u16* agg  = (u16*)(ws + 58161920);     // N x 128 bf16

  k_prep<<<128, 256, 0, stream>>>(Wp1, Ws1, Wn1, Wp2, Ws2, Wn2,
                                  wpT1, wc1T, wpT2, wc2T, cb);
  k_cb_hist<<<(NE + 8191) / 8192, 256, 0, stream>>>(dst, cb);
  k_cb_scan<<<1, 256, 0, stream>>>(cb, cbo, curB);
  k_part<<<(NE + 4095) / 4096, 256, 0, stream>>>(src, dst, curB, part);
  k_bsort<<<NB, 512, 0, stream>>>(part, cbo, rp, esrc);

  // layer 1: hp = relu(x@Wp1+bp1)
  k_gemm<128,128,128,128,512, true ,false,true ,false>
      <<<(NN + 127) / 128, 512, 0, stream>>>(x, nullptr, wpT1, bp1, hp);
  k_agg<<<(NN + 3) / 4, 256, 0, stream>>>(hp, rp, esrc, agg);
  // h = relu([x|agg]@Wc1+b1)  AND  hp = relu(h@Wp2+bp2)  (fused pool2)
  k_cgemm<<<(NN + 127) / 128, 512, 0, stream>>>(x, agg, wc1T, b1, wpT2, bp2, h, hp);
  // layer 2
  k_agg<<<(NN + 3) / 4, 256, 0, stream>>>(hp, rp, esrc, agg);
  k_gemm<256, 48, 40,128,512, false,true ,false,true >
      <<<(NN + 127) / 128, 512, 0, stream>>>(h, agg, wc2T, b2, d_out);
}

// Round 7
// 251.824 us; speedup vs baseline: 1.2025x; 1.0665x over previous
//
#include <hip/hip_runtime.h>
#include <stdint.h>

#define NN 100000
#define NE 1600000
#define NB 196          // coarse buckets of 512 nodes: bucket = dst >> 9

using u16 = unsigned short;
using u32 = unsigned int;

typedef __attribute__((ext_vector_type(8))) short bf16x8;
typedef __attribute__((ext_vector_type(4))) float f32x4;

__device__ inline u16 f2b(float f){
  u32 u = __float_as_uint(f);
  u32 r = (u + 0x7fffu + ((u >> 16) & 1u)) >> 16;
  return (u16)r;
}

// pack 8 consecutive floats (two float4) into a bf16x8 fragment
__device__ inline bf16x8 cvt8(const float* __restrict__ p){
  float4 a = *(const float4*)p;
  float4 b = *(const float4*)(p + 4);
  union { u32 w[4]; bf16x8 v; } u;
  u.w[0] = (u32)f2b(a.x) | ((u32)f2b(a.y) << 16);
  u.w[1] = (u32)f2b(a.z) | ((u32)f2b(a.w) << 16);
  u.w[2] = (u32)f2b(b.x) | ((u32)f2b(b.y) << 16);
  u.w[3] = (u32)f2b(b.z) | ((u32)f2b(b.w) << 16);
  return u.v;
}

// ------- weight prep: fp32 -> bf16, transposed [n][k]; also clears cb -------
__global__ void k_prep(const float* __restrict__ Wp1, const float* __restrict__ Ws1,
                       const float* __restrict__ Wn1, const float* __restrict__ Wp2,
                       const float* __restrict__ Ws2, const float* __restrict__ Wn2,
                       u16* __restrict__ wpT1, u16* __restrict__ wc1T,
                       u16* __restrict__ wpT2, u16* __restrict__ wc2T,
                       int* __restrict__ cb){
  int i = blockIdx.x * 256 + threadIdx.x;
  if (i < NB) cb[i] = 0;
  if (i < 16384){ int n = i >> 7, k = i & 127;
    wpT1[n*128 + k] = f2b(Wp1[k*128 + n]);
    wpT2[n*128 + k] = f2b(Wp2[k*128 + n]);
  }
  if (i < 32768){ int n = i >> 8, k = i & 255;
    float v = (k < 128) ? Ws1[k*128 + n] : Wn1[(k-128)*128 + n];
    wc1T[n*256 + k] = f2b(v);
  }
  if (i < 12288){ int n = i >> 8, k = i & 255;
    float v = 0.f;
    if (n < 40) v = (k < 128) ? Ws2[k*40 + n] : Wn2[(k-128)*40 + n];
    wc2T[n*256 + k] = f2b(v);
  }
}

// ---------------- CSR build: two-pass LDS-binned counting sort ----------------
__global__ __launch_bounds__(256) void k_cb_hist(const int* __restrict__ dst,
                                                 int* __restrict__ cb){
  __shared__ int h[NB];
  for (int i = threadIdx.x; i < NB; i += 256) h[i] = 0;
  __syncthreads();
  int e0 = blockIdx.x * 8192;
  #pragma unroll 4
  for (int j = 0; j < 32; j++){
    int e = e0 + j * 256 + threadIdx.x;
    if (e < NE) atomicAdd(&h[dst[e] >> 9], 1);
  }
  __syncthreads();
  for (int i = threadIdx.x; i < NB; i += 256)
    if (h[i]) atomicAdd(&cb[i], h[i]);
}

__global__ __launch_bounds__(256) void k_cb_scan(const int* __restrict__ cb,
                                                 int* __restrict__ cbo,
                                                 int* __restrict__ curB){
  __shared__ int s[256];
  int tid = threadIdx.x;
  int v = (tid < NB) ? cb[tid] : 0;
  s[tid] = v;
  __syncthreads();
  #pragma unroll
  for (int off = 1; off < 256; off <<= 1){
    int t = (tid >= off) ? s[tid - off] : 0;
    __syncthreads();
    s[tid] += t;
    __syncthreads();
  }
  int ex = s[tid] - v;
  if (tid < NB){ cbo[tid] = ex; curB[tid] = ex; }
  if (tid == 255) cbo[NB] = s[255];
}

__global__ __launch_bounds__(256) void k_part(const int* __restrict__ src,
                                              const int* __restrict__ dst,
                                              int* __restrict__ curB,
                                              int2* __restrict__ part){
  __shared__ int hist[256], scn[256], cur[256], base[256];
  __shared__ int2 stage[4096];
  const int tid = threadIdx.x;
  const int e0 = blockIdx.x * 4096;
  const int cnt = min(4096, NE - e0);
  hist[tid] = 0;
  __syncthreads();
  int2 ed[16];
  #pragma unroll
  for (int j = 0; j < 16; j++){
    int e = e0 + j * 256 + tid;
    if (e < NE){
      ed[j].x = src[e]; ed[j].y = dst[e];
      atomicAdd(&hist[ed[j].y >> 9], 1);
    }
  }
  __syncthreads();
  int hv = hist[tid];
  base[tid] = (tid < NB && hv) ? atomicAdd(&curB[tid], hv) : 0;
  scn[tid] = hv;
  __syncthreads();
  #pragma unroll
  for (int off = 1; off < 256; off <<= 1){
    int t = (tid >= off) ? scn[tid - off] : 0;
    __syncthreads();
    scn[tid] += t;
    __syncthreads();
  }
  int ex = scn[tid] - hv;
  scn[tid] = ex;
  cur[tid] = ex;
  __syncthreads();
  #pragma unroll
  for (int j = 0; j < 16; j++){
    int e = e0 + j * 256 + tid;
    if (e < NE){
      int slot = atomicAdd(&cur[ed[j].y >> 9], 1);
      stage[slot] = ed[j];
    }
  }
  __syncthreads();
  for (int i = tid; i < cnt; i += 256){
    int2 p = stage[i];
    int b = p.y >> 9;
    part[base[b] + (i - scn[b])] = p;
  }
}

__global__ __launch_bounds__(512) void k_bsort(const int2* __restrict__ part,
                                               const int* __restrict__ cbo,
                                               int* __restrict__ rp,
                                               int* __restrict__ esrc){
  __shared__ int cnt[512], sc[512], cur[512];
  const int tid = threadIdx.x;
  const int b = blockIdx.x;
  const int lo = cbo[b], hi = cbo[b + 1];
  cnt[tid] = 0;
  __syncthreads();
  for (int i = lo + tid; i < hi; i += 512)
    atomicAdd(&cnt[part[i].y & 511], 1);
  __syncthreads();
  sc[tid] = cnt[tid];
  __syncthreads();
  #pragma unroll
  for (int off = 1; off < 512; off <<= 1){
    int t = (tid >= off) ? sc[tid - off] : 0;
    __syncthreads();
    sc[tid] += t;
    __syncthreads();
  }
  int ex = sc[tid] - cnt[tid];
  int n = (b << 9) + tid;
  if (n < NN) rp[n] = lo + ex;
  if (b == NB - 1 && tid == 0) rp[NN] = hi;
  cur[tid] = lo + ex;
  __syncthreads();
  for (int i = lo + tid; i < hi; i += 512){
    int2 p = part[i];
    int pos = atomicAdd(&cur[p.y & 511], 1);
    esrc[pos] = p.x;
  }
}

// ---------------- segment-max aggregation (one wave per node) ----------------
// post-ReLU messages (>=0): packed-bf16 max == v_pk_max_u16, init 0 handles
// zero-in-degree. Half-wave per row (32x8B), 16 edges in flight per wave.
__global__ void k_agg(const u16* __restrict__ hp, const int* __restrict__ rp,
                      const int* __restrict__ esrc, u16* __restrict__ agg){
  int node = blockIdx.x * 4 + (threadIdx.x >> 6);
  if (node >= NN) return;
  const int lane = threadIdx.x & 63;
  const int half = lane >> 5;
  const int l32  = lane & 31;
  const int lo = rp[node], hi = rp[node + 1];
  u32 m0 = 0, m1 = 0;
  for (int i = lo; i < hi; i += 16){
    int s[8];
    #pragma unroll
    for (int j = 0; j < 8; j++){
      int ii = i + 2 * j + half; if (ii >= hi) ii = hi - 1;
      s[j] = esrc[ii];
    }
    uint2 v[8];
    #pragma unroll
    for (int j = 0; j < 8; j++)
      v[j] = *(const uint2*)&hp[(size_t)s[j] * 128 + l32 * 4];
    #pragma unroll
    for (int j = 0; j < 8; j++){
      asm("v_pk_max_u16 %0, %0, %1" : "+v"(m0) : "v"(v[j].x));
      asm("v_pk_max_u16 %0, %0, %1" : "+v"(m1) : "v"(v[j].y));
    }
  }
  u32 t0 = (u32)__shfl_xor((int)m0, 32);
  u32 t1 = (u32)__shfl_xor((int)m1, 32);
  asm("v_pk_max_u16 %0, %0, %1" : "+v"(m0) : "v"(t0));
  asm("v_pk_max_u16 %0, %0, %1" : "+v"(m1) : "v"(t1));
  if (half == 0)
    *(uint2*)&agg[(size_t)node * 128 + l32 * 4] = make_uint2(m0, m1);
}

// -------- barrier-free MFMA GEMM: out = [A1|A2] @ Wt^T + bias --------
// W (all NOUT x K) staged in LDS ONCE (single barrier); K-loop has NO barriers:
// each wave loads its own A fragments directly from global (16 rows x 64B
// contiguous chunks -> sector-coalesced, each element fetched exactly once).
// Rows >= NN clamp to NN-1 (C-write masked). fp32 A converted in-register.
// 16x16x32 MFMA; frag layouts m89-verified. Pitch K+8 elems: 16B-aligned rows,
// ~2-way bank aliasing per 16-lane phase (free, m136).
template<int K, int NOUT, int NOUTR, bool A1F32, bool HASA2, bool RELU, bool OUTF32>
__global__ __launch_bounds__(512)
void k_dgemm(const void* __restrict__ A1p, const u16* __restrict__ A2,
             const u16* __restrict__ Wt, const float* __restrict__ bias,
             void* __restrict__ outp)
{
  constexpr int KP  = K + 8;
  constexpr int NTI = NOUT / 16;
  __shared__ u16 W_lds[NOUT * KP];
  const int tid  = threadIdx.x;
  const int row0 = blockIdx.x * 128;
  const int wave = tid >> 6, lane = tid & 63;
  const int colb = lane & 15;
  const int koff = (lane >> 4) * 8;

  // stage full W once
  for (int c = tid; c < NOUT * (K / 8); c += 512){
    int n = c / (K / 8), kc = c % (K / 8);
    *(uint4*)&W_lds[n * KP + kc * 8] = *(const uint4*)&Wt[n * K + kc * 8];
  }
  __syncthreads();

  const int rowl = wave * 16 + colb;          // this lane's A row (frag layout)
  const int rA   = min(row0 + rowl, NN - 1);  // clamped for safe global reads

  f32x4 acc[NTI] = {};

  #pragma unroll
  for (int k0 = 0; k0 < K; k0 += 64){
    bf16x8 af0, af1;
    if (A1F32 && k0 < 128){
      const float* A = (const float*)A1p;
      af0 = cvt8(&A[(size_t)rA * 128 + k0 + koff]);
      af1 = cvt8(&A[(size_t)rA * 128 + k0 + 32 + koff]);
    } else {
      const u16* A = (HASA2 && k0 >= 128) ? A2 : (const u16*)A1p;
      int kb = (HASA2 && k0 >= 128) ? (k0 - 128) : k0;
      af0 = *(const bf16x8*)&A[(size_t)rA * 128 + kb + koff];
      af1 = *(const bf16x8*)&A[(size_t)rA * 128 + kb + 32 + koff];
    }
    #pragma unroll
    for (int nt = 0; nt < NTI; nt++){
      const u16* Wr = &W_lds[(nt * 16 + colb) * KP + k0];
      bf16x8 b0 = *(const bf16x8*)&Wr[koff];
      bf16x8 b1 = *(const bf16x8*)&Wr[32 + koff];
      acc[nt] = __builtin_amdgcn_mfma_f32_16x16x32_bf16(af0, b0, acc[nt], 0, 0, 0);
      acc[nt] = __builtin_amdgcn_mfma_f32_16x16x32_bf16(af1, b1, acc[nt], 0, 0, 0);
    }
  }

  const int rowc = wave * 16 + ((lane >> 4) << 2);   // C-frag base row
  #pragma unroll
  for (int nt = 0; nt < NTI; nt++){
    int col = nt * 16 + colb;
    if (col >= NOUTR) continue;
    float bv = bias[col];
    #pragma unroll
    for (int r = 0; r < 4; r++){
      int gr = row0 + rowc + r;
      if (gr >= NN) continue;
      float v = acc[nt][r] + bv;
      if (RELU) v = fmaxf(v, 0.f);
      if (OUTF32) ((float*)outp)[(size_t)gr * NOUTR + col] = v;
      else        ((u16*)outp)[(size_t)gr * NOUTR + col] = f2b(v);
    }
  }
}

// ---------------- host launch ----------------
extern "C" void kernel_launch(void* const* d_in, const int* in_sizes, int n_in,
                              void* d_out, int out_size, void* d_ws, size_t ws_size,
                              hipStream_t stream){
  const float* x   = (const float*)d_in[0];
  const int*   src = (const int*)d_in[1];
  const int*   dst = (const int*)d_in[2];
  const float* Wp1 = (const float*)d_in[3];
  const float* bp1 = (const float*)d_in[4];
  const float* Ws1 = (const float*)d_in[5];
  const float* Wn1 = (const float*)d_in[6];
  const float* b1  = (const float*)d_in[7];
  const float* Wp2 = (const float*)d_in[8];
  const float* bp2 = (const float*)d_in[9];
  const float* Ws2 = (const float*)d_in[10];
  const float* Wn2 = (const float*)d_in[11];
  const float* b2  = (const float*)d_in[12];

  char* ws = (char*)d_ws;
  u16* wpT1 = (u16*)(ws + 0);            // 128x128 bf16
  u16* wc1T = (u16*)(ws + 32768);        // 128x256 bf16
  u16* wpT2 = (u16*)(ws + 98304);        // 128x128 bf16
  u16* wc2T = (u16*)(ws + 131072);       // 48x256 bf16 (cols 40..47 zero)
  int* cb   = (int*)(ws + 155648);       // NB bucket counts
  int* cbo  = (int*)(ws + 157696);       // NB+1 bucket offsets
  int* curB = (int*)(ws + 159744);       // NB reservation cursors
  int* rp   = (int*)(ws + 161792);       // N+1 row pointers
  int2* part= (int2*)(ws + 561920);      // E pairs, bucket-grouped (12.8 MB)
  u16* h    = (u16*)(ws + 561920);       // N x 128 bf16 (aliases part; part dead first)
  int* esrc = (int*)(ws + 26161920);     // E src ids sorted by dst (6.4 MB)
  u16* hp   = (u16*)(ws + 32561920);     // N x 128 bf16
  u16* agg  = (u16*)(ws + 58161920);     // N x 128 bf16

  k_prep<<<128, 256, 0, stream>>>(Wp1, Ws1, Wn1, Wp2, Ws2, Wn2,
                                  wpT1, wc1T, wpT2, wc2T, cb);
  k_cb_hist<<<(NE + 8191) / 8192, 256, 0, stream>>>(dst, cb);
  k_cb_scan<<<1, 256, 0, stream>>>(cb, cbo, curB);
  k_part<<<(NE + 4095) / 4096, 256, 0, stream>>>(src, dst, curB, part);
  k_bsort<<<NB, 512, 0, stream>>>(part, cbo, rp, esrc);

  // layer 1
  k_dgemm<128,128,128, true ,false,true ,false>
      <<<(NN + 127) / 128, 512, 0, stream>>>(x, nullptr, wpT1, bp1, hp);
  k_agg<<<(NN + 3) / 4, 256, 0, stream>>>(hp, rp, esrc, agg);
  k_dgemm<256,128,128, true ,true ,true ,false>
      <<<(NN + 127) / 128, 512, 0, stream>>>(x, agg, wc1T, b1, h);
  // layer 2
  k_dgemm<128,128,128, false,false,true ,false>
      <<<(NN + 127) / 128, 512, 0, stream>>>(h, nullptr, wpT2, bp2, hp);
  k_agg<<<(NN + 3) / 4, 256, 0, stream>>>(hp, rp, esrc, agg);
  k_dgemm<256, 48, 40, false,true ,false,true >
      <<<(NN + 127) / 128, 512, 0, stream>>>(h, agg, wc2T, b2, d_out);
}

// Round 8
// 250.966 us; speedup vs baseline: 1.2066x; 1.0034x over previous
//
#include <hip/hip_runtime.h>
#include <stdint.h>

#define NN 100000
#define NE 1600000
#define NB 391          // buckets of 256 nodes: bucket = dst >> 8

using u16 = unsigned short;
using u32 = unsigned int;

typedef __attribute__((ext_vector_type(8))) short bf16x8;
typedef __attribute__((ext_vector_type(4))) float f32x4;

__device__ inline u16 f2b(float f){
  u32 u = __float_as_uint(f);
  u32 r = (u + 0x7fffu + ((u >> 16) & 1u)) >> 16;
  return (u16)r;
}

// pack 8 consecutive floats (two float4) into a bf16x8 fragment
__device__ inline bf16x8 cvt8(const float* __restrict__ p){
  float4 a = *(const float4*)p;
  float4 b = *(const float4*)(p + 4);
  union { u32 w[4]; bf16x8 v; } u;
  u.w[0] = (u32)f2b(a.x) | ((u32)f2b(a.y) << 16);
  u.w[1] = (u32)f2b(a.z) | ((u32)f2b(a.w) << 16);
  u.w[2] = (u32)f2b(b.x) | ((u32)f2b(b.y) << 16);
  u.w[3] = (u32)f2b(b.z) | ((u32)f2b(b.w) << 16);
  return u.v;
}

// ------- weight prep: fp32 -> bf16, transposed [n][k]; also clears cb -------
__global__ void k_prep(const float* __restrict__ Wp1, const float* __restrict__ Ws1,
                       const float* __restrict__ Wn1, const float* __restrict__ Wp2,
                       const float* __restrict__ Ws2, const float* __restrict__ Wn2,
                       u16* __restrict__ wpT1, u16* __restrict__ wc1T,
                       u16* __restrict__ wpT2, u16* __restrict__ wc2T,
                       int* __restrict__ cb){
  int i = blockIdx.x * 256 + threadIdx.x;
  if (i < NB) cb[i] = 0;
  if (i < 16384){ int n = i >> 7, k = i & 127;
    wpT1[n*128 + k] = f2b(Wp1[k*128 + n]);
    wpT2[n*128 + k] = f2b(Wp2[k*128 + n]);
  }
  if (i < 32768){ int n = i >> 8, k = i & 255;
    float v = (k < 128) ? Ws1[k*128 + n] : Wn1[(k-128)*128 + n];
    wc1T[n*256 + k] = f2b(v);
  }
  if (i < 12288){ int n = i >> 8, k = i & 255;
    float v = 0.f;
    if (n < 40) v = (k < 128) ? Ws2[k*40 + n] : Wn2[(k-128)*40 + n];
    wc2T[n*256 + k] = f2b(v);
  }
}

// ---------------- CSR build: two-pass LDS-binned counting sort ----------------
// pass 0: coarse bucket histogram, full occupancy, 4 edges/thread
__global__ __launch_bounds__(512) void k_cb_hist(const int* __restrict__ dst,
                                                 int* __restrict__ cb){
  __shared__ int h[NB];
  for (int i = threadIdx.x; i < NB; i += 512) h[i] = 0;
  __syncthreads();
  int e0 = blockIdx.x * 2048 + threadIdx.x;
  #pragma unroll
  for (int j = 0; j < 4; j++){
    int e = e0 + j * 512;
    if (e < NE) atomicAdd(&h[dst[e] >> 8], 1);
  }
  __syncthreads();
  for (int i = threadIdx.x; i < NB; i += 512)
    if (h[i]) atomicAdd(&cb[i], h[i]);
}

// exclusive scan of NB (<=512) bucket counts
__global__ __launch_bounds__(512) void k_cb_scan(const int* __restrict__ cb,
                                                 int* __restrict__ cbo,
                                                 int* __restrict__ curB){
  __shared__ int s[512];
  int tid = threadIdx.x;
  int v = (tid < NB) ? cb[tid] : 0;
  s[tid] = v;
  __syncthreads();
  #pragma unroll
  for (int off = 1; off < 512; off <<= 1){
    int t = (tid >= off) ? s[tid - off] : 0;
    __syncthreads();
    s[tid] += t;
    __syncthreads();
  }
  int ex = s[tid] - v;
  if (tid < NB){ cbo[tid] = ex; curB[tid] = ex; }
  if (tid == 511) cbo[NB] = s[511];
}

// pass 1: partition edges into bucket-contiguous regions (LDS-staged so global
// writes are contiguous runs); part stores packed (dstLocal:8 | src:17) u32
__global__ __launch_bounds__(1024) void k_part(const int* __restrict__ src,
                                               const int* __restrict__ dst,
                                               int* __restrict__ curB,
                                               u32* __restrict__ part){
  __shared__ int hist[NB], scn[NB], cur[NB], base[NB];
  __shared__ int2 stage[4096];
  const int tid = threadIdx.x;
  const int e0 = blockIdx.x * 4096;
  const int cnt = min(4096, NE - e0);
  for (int i = tid; i < NB; i += 1024) hist[i] = 0;
  __syncthreads();
  int2 ed[4];
  #pragma unroll
  for (int j = 0; j < 4; j++){
    int e = e0 + j * 1024 + tid;
    if (e < NE){
      ed[j].x = src[e]; ed[j].y = dst[e];
      atomicAdd(&hist[ed[j].y >> 8], 1);
    }
  }
  __syncthreads();
  int hv = (tid < NB) ? hist[tid] : 0;
  if (tid < NB) base[tid] = hv ? atomicAdd(&curB[tid], hv) : 0;
  // exclusive scan of hist over 512 lanes (NB <= 512); all 1024 threads hit syncs
  #pragma unroll
  for (int off = 1; off < 512; off <<= 1){
    int t = 0;
    if (tid < 512 && tid >= off && tid - off < NB) t = hist[tid - off];
    __syncthreads();
    if (tid < NB) hist[tid] += t;
    __syncthreads();
  }
  if (tid < NB){ int ex = hist[tid] - hv; scn[tid] = ex; cur[tid] = ex; }
  __syncthreads();
  #pragma unroll
  for (int j = 0; j < 4; j++){
    int e = e0 + j * 1024 + tid;
    if (e < NE){
      int slot = atomicAdd(&cur[ed[j].y >> 8], 1);
      stage[slot] = ed[j];
    }
  }
  __syncthreads();
  for (int i = tid; i < cnt; i += 1024){
    int2 p = stage[i];
    int b = p.y >> 8;
    part[base[b] + (i - scn[b])] = ((u32)(p.y & 255) << 17) | (u32)p.x;
  }
}

// pass 2: one wg per bucket: per-node histogram+scan -> rp, scatter src ids
// into the bucket's contiguous esrc region
__global__ __launch_bounds__(256) void k_bsort(const u32* __restrict__ part,
                                               const int* __restrict__ cbo,
                                               int* __restrict__ rp,
                                               int* __restrict__ esrc){
  __shared__ int cnt[256], sc[256], cur[256];
  const int tid = threadIdx.x;
  const int b = blockIdx.x;
  const int lo = cbo[b], hi = cbo[b + 1];
  cnt[tid] = 0;
  __syncthreads();
  for (int i = lo + tid; i < hi; i += 256)
    atomicAdd(&cnt[part[i] >> 17], 1);
  __syncthreads();
  sc[tid] = cnt[tid];
  __syncthreads();
  #pragma unroll
  for (int off = 1; off < 256; off <<= 1){
    int t = (tid >= off) ? sc[tid - off] : 0;
    __syncthreads();
    sc[tid] += t;
    __syncthreads();
  }
  int ex = sc[tid] - cnt[tid];
  int n = (b << 8) + tid;
  if (n < NN) rp[n] = lo + ex;
  if (b == NB - 1 && tid == 0) rp[NN] = hi;
  cur[tid] = lo + ex;
  __syncthreads();
  for (int i = lo + tid; i < hi; i += 256){
    u32 p = part[i];
    int pos = atomicAdd(&cur[p >> 17], 1);
    esrc[pos] = (int)(p & 0x1FFFFu);
  }
}

// ---------------- segment-max aggregation (one wave per node) ----------------
// post-ReLU messages (>=0): packed-bf16 max == v_pk_max_u16, init 0 handles
// zero-in-degree. Half-wave per row (32x8B), 16 edges in flight per wave.
// At its structural floor: FETCH ~177MB = per-XCD compulsory miss traffic
// (row touched by an XCD w.p. 1-e^-2), delivered at the ~3.6TB/s L2-fill ceiling.
__global__ void k_agg(const u16* __restrict__ hp, const int* __restrict__ rp,
                      const int* __restrict__ esrc, u16* __restrict__ agg){
  int node = blockIdx.x * 4 + (threadIdx.x >> 6);
  if (node >= NN) return;
  const int lane = threadIdx.x & 63;
  const int half = lane >> 5;
  const int l32  = lane & 31;
  const int lo = rp[node], hi = rp[node + 1];
  u32 m0 = 0, m1 = 0;
  for (int i = lo; i < hi; i += 16){
    int s[8];
    #pragma unroll
    for (int j = 0; j < 8; j++){
      int ii = i + 2 * j + half; if (ii >= hi) ii = hi - 1;
      s[j] = esrc[ii];
    }
    uint2 v[8];
    #pragma unroll
    for (int j = 0; j < 8; j++)
      v[j] = *(const uint2*)&hp[(size_t)s[j] * 128 + l32 * 4];
    #pragma unroll
    for (int j = 0; j < 8; j++){
      asm("v_pk_max_u16 %0, %0, %1" : "+v"(m0) : "v"(v[j].x));
      asm("v_pk_max_u16 %0, %0, %1" : "+v"(m1) : "v"(v[j].y));
    }
  }
  u32 t0 = (u32)__shfl_xor((int)m0, 32);
  u32 t1 = (u32)__shfl_xor((int)m1, 32);
  asm("v_pk_max_u16 %0, %0, %1" : "+v"(m0) : "v"(t0));
  asm("v_pk_max_u16 %0, %0, %1" : "+v"(m1) : "v"(t1));
  if (half == 0)
    *(uint2*)&agg[(size_t)node * 128 + l32 * 4] = make_uint2(m0, m1);
}

// -------- barrier-free MFMA GEMM: out = [A1|A2] @ Wt^T + bias --------
// W staged in LDS ONCE (single barrier); K-loop has NO barriers: each wave
// loads its own A fragments directly from global (rows >= NN clamp to NN-1,
// C-write masked). fp32 A converted in-register. Frag layouts m89-verified.
template<int K, int NOUT, int NOUTR, bool A1F32, bool HASA2, bool RELU, bool OUTF32>
__global__ __launch_bounds__(512)
void k_dgemm(const void* __restrict__ A1p, const u16* __restrict__ A2,
             const u16* __restrict__ Wt, const float* __restrict__ bias,
             void* __restrict__ outp)
{
  constexpr int KP  = K + 8;
  constexpr int NTI = NOUT / 16;
  __shared__ u16 W_lds[NOUT * KP];
  const int tid  = threadIdx.x;
  const int row0 = blockIdx.x * 128;
  const int wave = tid >> 6, lane = tid & 63;
  const int colb = lane & 15;
  const int koff = (lane >> 4) * 8;

  for (int c = tid; c < NOUT * (K / 8); c += 512){
    int n = c / (K / 8), kc = c % (K / 8);
    *(uint4*)&W_lds[n * KP + kc * 8] = *(const uint4*)&Wt[n * K + kc * 8];
  }
  __syncthreads();

  const int rowl = wave * 16 + colb;
  const int rA   = min(row0 + rowl, NN - 1);

  f32x4 acc[NTI] = {};

  #pragma unroll
  for (int k0 = 0; k0 < K; k0 += 64){
    bf16x8 af0, af1;
    if (A1F32 && k0 < 128){
      const float* A = (const float*)A1p;
      af0 = cvt8(&A[(size_t)rA * 128 + k0 + koff]);
      af1 = cvt8(&A[(size_t)rA * 128 + k0 + 32 + koff]);
    } else {
      const u16* A = (HASA2 && k0 >= 128) ? A2 : (const u16*)A1p;
      int kb = (HASA2 && k0 >= 128) ? (k0 - 128) : k0;
      af0 = *(const bf16x8*)&A[(size_t)rA * 128 + kb + koff];
      af1 = *(const bf16x8*)&A[(size_t)rA * 128 + kb + 32 + koff];
    }
    #pragma unroll
    for (int nt = 0; nt < NTI; nt++){
      const u16* Wr = &W_lds[(nt * 16 + colb) * KP + k0];
      bf16x8 b0 = *(const bf16x8*)&Wr[koff];
      bf16x8 b1 = *(const bf16x8*)&Wr[32 + koff];
      acc[nt] = __builtin_amdgcn_mfma_f32_16x16x32_bf16(af0, b0, acc[nt], 0, 0, 0);
      acc[nt] = __builtin_amdgcn_mfma_f32_16x16x32_bf16(af1, b1, acc[nt], 0, 0, 0);
    }
  }

  const int rowc = wave * 16 + ((lane >> 4) << 2);
  #pragma unroll
  for (int nt = 0; nt < NTI; nt++){
    int col = nt * 16 + colb;
    if (col >= NOUTR) continue;
    float bv = bias[col];
    #pragma unroll
    for (int r = 0; r < 4; r++){
      int gr = row0 + rowc + r;
      if (gr >= NN) continue;
      float v = acc[nt][r] + bv;
      if (RELU) v = fmaxf(v, 0.f);
      if (OUTF32) ((float*)outp)[(size_t)gr * NOUTR + col] = v;
      else        ((u16*)outp)[(size_t)gr * NOUTR + col] = f2b(v);
    }
  }
}

// ---------------- host launch ----------------
extern "C" void kernel_launch(void* const* d_in, const int* in_sizes, int n_in,
                              void* d_out, int out_size, void* d_ws, size_t ws_size,
                              hipStream_t stream){
  const float* x   = (const float*)d_in[0];
  const int*   src = (const int*)d_in[1];
  const int*   dst = (const int*)d_in[2];
  const float* Wp1 = (const float*)d_in[3];
  const float* bp1 = (const float*)d_in[4];
  const float* Ws1 = (const float*)d_in[5];
  const float* Wn1 = (const float*)d_in[6];
  const float* b1  = (const float*)d_in[7];
  const float* Wp2 = (const float*)d_in[8];
  const float* bp2 = (const float*)d_in[9];
  const float* Ws2 = (const float*)d_in[10];
  const float* Wn2 = (const float*)d_in[11];
  const float* b2  = (const float*)d_in[12];

  char* ws = (char*)d_ws;
  u16* wpT1 = (u16*)(ws + 0);            // 128x128 bf16
  u16* wc1T = (u16*)(ws + 32768);        // 128x256 bf16
  u16* wpT2 = (u16*)(ws + 98304);        // 128x128 bf16
  u16* wc2T = (u16*)(ws + 131072);       // 48x256 bf16 (cols 40..47 zero)
  int* cb   = (int*)(ws + 155648);       // NB bucket counts
  int* cbo  = (int*)(ws + 157696);       // NB+1 bucket offsets
  int* curB = (int*)(ws + 159744);       // NB reservation cursors
  int* rp   = (int*)(ws + 161792);       // N+1 row pointers
  u32* part = (u32*)(ws + 561920);       // E packed (dstLocal|src), bucket-grouped (6.4 MB)
  u16* h    = (u16*)(ws + 561920);       // N x 128 bf16 (aliases part; part dead first)
  int* esrc = (int*)(ws + 26161920);     // E src ids sorted by dst (6.4 MB)
  u16* hp   = (u16*)(ws + 32561920);     // N x 128 bf16
  u16* agg  = (u16*)(ws + 58161920);     // N x 128 bf16

  k_prep<<<128, 256, 0, stream>>>(Wp1, Ws1, Wn1, Wp2, Ws2, Wn2,
                                  wpT1, wc1T, wpT2, wc2T, cb);
  k_cb_hist<<<(NE + 2047) / 2048, 512, 0, stream>>>(dst, cb);
  k_cb_scan<<<1, 512, 0, stream>>>(cb, cbo, curB);
  k_part<<<(NE + 4095) / 4096, 1024, 0, stream>>>(src, dst, curB, part);
  k_bsort<<<NB, 256, 0, stream>>>(part, cbo, rp, esrc);

  // layer 1
  k_dgemm<128,128,128, true ,false,true ,false>
      <<<(NN + 127) / 128, 512, 0, stream>>>(x, nullptr, wpT1, bp1, hp);
  k_agg<<<(NN + 3) / 4, 256, 0, stream>>>(hp, rp, esrc, agg);
  k_dgemm<256,128,128, true ,true ,true ,false>
      <<<(NN + 127) / 128, 512, 0, stream>>>(x, agg, wc1T, b1, h);
  // layer 2
  k_dgemm<128,128,128, false,false,true ,false>
      <<<(NN + 127) / 128, 512, 0, stream>>>(h, nullptr, wpT2, bp2, hp);
  k_agg<<<(NN + 3) / 4, 256, 0, stream>>>(hp, rp, esrc, agg);
  k_dgemm<256, 48, 40, false,true ,false,true >
      <<<(NN + 127) / 128, 512, 0, stream>>>(h, agg, wc2T, b2, d_out);
}